// Round 1
// baseline (558.129 us; speedup 1.0000x reference)
//
#include <hip/hip_runtime.h>
#include <stdint.h>

// AnchorTargetLayer for MI355X.
// N = 331776 anchors (192*192*9), G = 128 gt boxes.
// Outputs (flat in d_out, all float32):
//   [0,N)      labels (-1/0/1)
//   [N,5N)     bbox targets (4 per anchor)
//   [5N,9N)    inside weights
//   [9N,13N)   outside weights
//
// RNG: JAX threefry2x32, key(42), split, uniform. TF_PARTITIONABLE selects
// jax_threefry_partitionable semantics (modern default). If labels mismatch
// with absmax ~2.0, set TF_PARTITIONABLE 0 (legacy iota-pair counters).
#define TF_PARTITIONABLE 1

#define NBINS 4096
#define CAND_CAP 4096
#define GMAX 128
#define RPN_NEG 0.3f
#define RPN_POS 0.7f

struct U2 { uint32_t a, b; };

__host__ __device__ constexpr U2 tf2x32(uint32_t k0, uint32_t k1, uint32_t x0, uint32_t x1) {
  uint32_t ks2 = k0 ^ k1 ^ 0x1BD11BDAu;
  x0 += k0; x1 += k1;
#define TFR(r) { x0 += x1; x1 = (uint32_t)((x1 << (r)) | (x1 >> (32 - (r)))); x1 ^= x0; }
  TFR(13) TFR(15) TFR(26) TFR(6)
  x0 += k1; x1 += ks2 + 1u;
  TFR(17) TFR(29) TFR(16) TFR(24)
  x0 += ks2; x1 += k0 + 2u;
  TFR(13) TFR(15) TFR(26) TFR(6)
  x0 += k0; x1 += k1 + 3u;
  TFR(17) TFR(29) TFR(16) TFR(24)
  x0 += k1; x1 += ks2 + 4u;
  TFR(13) TFR(15) TFR(26) TFR(6)
  x0 += ks2; x1 += k0 + 5u;
#undef TFR
  return U2{x0, x1};
}

#if TF_PARTITIONABLE
// foldlike split: kf = cipher(key,(0,0)), kb = cipher(key,(0,1))
constexpr U2 KEYF = tf2x32(0u, 42u, 0u, 0u);
constexpr U2 KEYB = tf2x32(0u, 42u, 0u, 1u);
#else
// original split: counts iota(4) -> pairs (0,2),(1,3); kf = x0 words, kb = x1 words
constexpr U2 C02 = tf2x32(0u, 42u, 0u, 2u);
constexpr U2 C13 = tf2x32(0u, 42u, 1u, 3u);
constexpr U2 KEYF = U2{C02.a, C13.a};
constexpr U2 KEYB = U2{C02.b, C13.b};
#endif

__device__ __forceinline__ float tf_uniform(uint32_t k0, uint32_t k1, uint32_t i, uint32_t N) {
#if TF_PARTITIONABLE
  U2 r = tf2x32(k0, k1, 0u, i);
  uint32_t bits = r.a ^ r.b;
#else
  uint32_t h = N >> 1;  // N even
  uint32_t bits;
  if (i < h) { U2 r = tf2x32(k0, k1, i, i + h); bits = r.a; }
  else       { U2 r = tf2x32(k0, k1, i - h, i); bits = r.b; }
#endif
  return __uint_as_float((bits >> 9) | 0x3f800000u) - 1.0f;
}

// IoU, Pascal +1 convention. No fma-contraction so bits match the CPU ref.
__device__ __forceinline__ float iou_f(float ax1, float ay1, float ax2, float ay2,
                                       float gx1, float gy1, float gx2, float gy2) {
#pragma clang fp contract(off)
  float iw = fmaxf(fminf(ax2, gx2) - fmaxf(ax1, gx1) + 1.0f, 0.0f);
  float ih = fmaxf(fminf(ay2, gy2) - fmaxf(ay1, gy1) + 1.0f, 0.0f);
  float inter = iw * ih;
  float aa = (ax2 - ax1 + 1.0f) * (ay2 - ay1 + 1.0f);
  float ga = (gx2 - gx1 + 1.0f) * (gy2 - gy1 + 1.0f);
  return inter / (aa + ga - inter);
}

__global__ __launch_bounds__(256) void k_init(uint32_t* scalars, uint32_t* hist) {
  int i = blockIdx.x * 256 + threadIdx.x;
  if (i < 32) scalars[i] = 0u;
  if (i < 2 * NBINS) hist[i] = 0u;
}

// per-gt max of mov (= iou for inside rows, -1 for outside rows)
__global__ __launch_bounds__(256) void k_gt_max(const float4* __restrict__ anchors,
                                                const float* __restrict__ gt,
                                                const float* __restrict__ im_info,
                                                int N, float* __restrict__ gt_max) {
  int g = blockIdx.x;
  float gx1 = gt[g * 5 + 0], gy1 = gt[g * 5 + 1], gx2 = gt[g * 5 + 2], gy2 = gt[g * 5 + 3];
  float imH = im_info[0], imW = im_info[1];
  float local = -1.0f;
  for (int i = threadIdx.x; i < N; i += 256) {
    float4 a = anchors[i];
    if (a.x >= 0.0f && a.y >= 0.0f && a.z < imW && a.w < imH) {
      local = fmaxf(local, iou_f(a.x, a.y, a.z, a.w, gx1, gy1, gx2, gy2));
    }
  }
  __shared__ float red[256];
  red[threadIdx.x] = local;
  __syncthreads();
  for (int s = 128; s > 0; s >>= 1) {
    if (threadIdx.x < s) red[threadIdx.x] = fmaxf(red[threadIdx.x], red[threadIdx.x + s]);
    __syncthreads();
  }
  if (threadIdx.x == 0) gt_max[g] = red[0];
}

// per-anchor: argmax, pre-subsample label; append fg/bg (idx,uniform) lists + histograms
__global__ __launch_bounds__(256) void k_labels(
    const float4* __restrict__ anchors, const float* __restrict__ gt,
    const float* __restrict__ im_info, int N, int G,
    const float* __restrict__ gt_max, int* __restrict__ amax, int8_t* __restrict__ label,
    uint32_t* __restrict__ scalars, uint32_t* __restrict__ hist_f, uint32_t* __restrict__ hist_b,
    int* __restrict__ fgIdx, float* __restrict__ fgVal,
    int* __restrict__ bgIdx, float* __restrict__ bgVal) {
  __shared__ float4 sgt[GMAX];
  __shared__ float sgm[GMAX];
  __shared__ uint32_t lcnt[2], lbase[2];
  if (threadIdx.x < 2) lcnt[threadIdx.x] = 0u;
  for (int t = threadIdx.x; t < G; t += 256) {
    sgt[t] = make_float4(gt[t * 5 + 0], gt[t * 5 + 1], gt[t * 5 + 2], gt[t * 5 + 3]);
    sgm[t] = gt_max[t];
  }
  __syncthreads();
  int i = blockIdx.x * 256 + threadIdx.x;
  int cls = -1;           // 0 = fg, 1 = bg
  float val = 0.0f;
  uint32_t my = 0u;
  if (i < N) {
    float4 a = anchors[i];
    float imH = im_info[0], imW = im_info[1];
    bool inside = (a.x >= 0.0f && a.y >= 0.0f && a.z < imW && a.w < imH);
    int lab = -1, am = 0;
    if (inside) {
      float best = -1.0f;
      bool isbest = false;
      for (int g = 0; g < G; ++g) {
        float4 gb = sgt[g];
        float v = iou_f(a.x, a.y, a.z, a.w, gb.x, gb.y, gb.z, gb.w);
        if (v > best) { best = v; am = g; }     // first-max == jnp.argmax
        if (v == sgm[g]) isbest = true;         // tie set vs per-gt max
      }
      if (best < RPN_NEG) lab = 0;
      if (isbest) lab = -lab;                    // -(-1)=1, -(0)=0 (quirk kept)
      if (best >= RPN_POS) lab = 1;
    }
    amax[i] = am;
    label[i] = (int8_t)lab;
    if (lab == 1) {
      cls = 0; val = tf_uniform(KEYF.a, KEYF.b, (uint32_t)i, (uint32_t)N);
      my = atomicAdd(&lcnt[0], 1u);
      int b = (int)(val * (float)NBINS); if (b > NBINS - 1) b = NBINS - 1;
      atomicAdd(&hist_f[b], 1u);
    } else if (lab == 0) {
      cls = 1; val = tf_uniform(KEYB.a, KEYB.b, (uint32_t)i, (uint32_t)N);
      my = atomicAdd(&lcnt[1], 1u);
      int b = (int)(val * (float)NBINS); if (b > NBINS - 1) b = NBINS - 1;
      atomicAdd(&hist_b[b], 1u);
    }
  }
  __syncthreads();
  if (threadIdx.x == 0) {
    lbase[0] = lcnt[0] ? atomicAdd(&scalars[0], lcnt[0]) : 0u;
    lbase[1] = lcnt[1] ? atomicAdd(&scalars[1], lcnt[1]) : 0u;
  }
  __syncthreads();
  if (cls == 0) { uint32_t p = lbase[0] + my; fgIdx[p] = i; fgVal[p] = val; }
  else if (cls == 1) { uint32_t p = lbase[1] + my; bgIdx[p] = i; bgVal[p] = val; }
}

// find cutoff buckets: smallest T with cum(0..T) >= k; base = cum(0..T-1)
__global__ void k_select(uint32_t* scalars, const uint32_t* __restrict__ hist) {
  if (threadIdx.x != 0 || blockIdx.x != 0) return;
  uint32_t F = scalars[0], B = scalars[1];
  uint32_t k_f = F > 128u ? 128u : F;
  uint32_t k_b = 256u - k_f;
  uint32_t T_f = NBINS, base_f = 0u;
  if (F > k_f) {
    uint32_t cum = 0u;
    for (int b = 0; b < NBINS; ++b) {
      uint32_t c = hist[b];
      if (cum + c >= k_f) { T_f = (uint32_t)b; base_f = cum; break; }
      cum += c;
    }
  }
  uint32_t T_b = NBINS, base_b = 0u;
  if (B > k_b) {
    uint32_t cum = 0u;
    for (int b = 0; b < NBINS; ++b) {
      uint32_t c = hist[NBINS + b];
      if (cum + c >= k_b) { T_b = (uint32_t)b; base_b = cum; break; }
      cum += c;
    }
  }
  uint32_t kept = k_f + (B < k_b ? B : k_b);
  scalars[4] = T_f; scalars[5] = base_f;
  scalars[6] = T_b; scalars[7] = base_b;
  scalars[8] = k_b; scalars[9] = k_f;
  ((float*)scalars)[12] = kept ? (1.0f / (float)kept) : 0.0f;  // 1/num_ex
}

// drop entries past cutoff bucket; collect cutoff-bucket candidates
__global__ __launch_bounds__(256) void k_cands(uint32_t* scalars, int8_t* __restrict__ label,
    const int* __restrict__ fgIdx, const float* __restrict__ fgVal,
    const int* __restrict__ bgIdx, const float* __restrict__ bgVal,
    int* __restrict__ fcIdx, float* __restrict__ fcVal,
    int* __restrict__ bcIdx, float* __restrict__ bcVal) {
  uint32_t j = blockIdx.x * 256 + threadIdx.x;
  uint32_t F = scalars[0], B = scalars[1];
  uint32_t T_f = scalars[4], T_b = scalars[6];
  if (j < F) {
    float v = fgVal[j];
    uint32_t b = (uint32_t)(v * (float)NBINS); if (b > NBINS - 1) b = NBINS - 1;
    if (b > T_f) label[fgIdx[j]] = -1;
    else if (b == T_f) {
      uint32_t p = atomicAdd(&scalars[2], 1u);
      if (p < CAND_CAP) { fcIdx[p] = fgIdx[j]; fcVal[p] = v; }
    }
  }
  if (j < B) {
    float v = bgVal[j];
    uint32_t b = (uint32_t)(v * (float)NBINS); if (b > NBINS - 1) b = NBINS - 1;
    if (b > T_b) label[bgIdx[j]] = -1;
    else if (b == T_b) {
      uint32_t p = atomicAdd(&scalars[3], 1u);
      if (p < CAND_CAP) { bcIdx[p] = bgIdx[j]; bcVal[p] = v; }
    }
  }
}

// exact stable rank (value, then index — matches stable argsort) within cutoff bucket
__global__ __launch_bounds__(256) void k_rank(const uint32_t* __restrict__ scalars,
    int8_t* __restrict__ label,
    const int* __restrict__ fcIdx, const float* __restrict__ fcVal,
    const int* __restrict__ bcIdx, const float* __restrict__ bcVal) {
  uint32_t nf = scalars[2]; if (nf > CAND_CAP) nf = CAND_CAP;
  uint32_t nb = scalars[3]; if (nb > CAND_CAP) nb = CAND_CAP;
  uint32_t base_f = scalars[5], base_b = scalars[7];
  uint32_t k_f = scalars[9], k_b = scalars[8];
  for (uint32_t c = threadIdx.x; c < nf; c += 256) {
    float v = fcVal[c]; int idx = fcIdx[c];
    uint32_t r = base_f;
    for (uint32_t c2 = 0; c2 < nf; ++c2) {
      float v2 = fcVal[c2]; int i2 = fcIdx[c2];
      if (v2 < v || (v2 == v && i2 < idx)) r++;
    }
    if (r >= k_f) label[idx] = -1;
  }
  for (uint32_t c = threadIdx.x; c < nb; c += 256) {
    float v = bcVal[c]; int idx = bcIdx[c];
    uint32_t r = base_b;
    for (uint32_t c2 = 0; c2 < nb; ++c2) {
      float v2 = bcVal[c2]; int i2 = bcIdx[c2];
      if (v2 < v || (v2 == v && i2 < idx)) r++;
    }
    if (r >= k_b) label[idx] = -1;
  }
}

__global__ __launch_bounds__(256) void k_output(const float4* __restrict__ anchors,
    const float* __restrict__ gt, const float* __restrict__ im_info, int N,
    const int* __restrict__ amax, const int8_t* __restrict__ label,
    const uint32_t* __restrict__ scalars, float* __restrict__ out) {
#pragma clang fp contract(off)
  int i = blockIdx.x * 256 + threadIdx.x;
  if (i >= N) return;
  float4 a = anchors[i];
  float imH = im_info[0], imW = im_info[1];
  bool inside = (a.x >= 0.0f && a.y >= 0.0f && a.z < imW && a.w < imH);
  int lab = label[i];
  out[i] = (float)lab;
  float4 t = make_float4(0.0f, 0.0f, 0.0f, 0.0f);
  if (inside) {
    int g = amax[i];
    float gx1 = gt[g * 5 + 0], gy1 = gt[g * 5 + 1], gx2 = gt[g * 5 + 2], gy2 = gt[g * 5 + 3];
    float ew = a.z - a.x + 1.0f, eh = a.w - a.y + 1.0f;
    float ecx = a.x + 0.5f * ew, ecy = a.y + 0.5f * eh;
    float gw = gx2 - gx1 + 1.0f, gh = gy2 - gy1 + 1.0f;
    float gcx = gx1 + 0.5f * gw, gcy = gy1 + 0.5f * gh;
    t.x = (gcx - ecx) / ew;
    t.y = (gcy - ecy) / eh;
    t.z = logf(gw / ew);
    t.w = logf(gh / eh);
  }
  ((float4*)(out + (size_t)N))[i] = t;
  float iw = (lab == 1) ? 1.0f : 0.0f;
  ((float4*)(out + 5 * (size_t)N))[i] = make_float4(iw, iw, iw, iw);
  float inv = ((const float*)scalars)[12];
  float ow = (lab == 0 || lab == 1) ? inv : 0.0f;
  ((float4*)(out + 9 * (size_t)N))[i] = make_float4(ow, ow, ow, ow);
}

extern "C" void kernel_launch(void* const* d_in, const int* in_sizes, int n_in,
                              void* d_out, int out_size, void* d_ws, size_t ws_size,
                              hipStream_t stream) {
  const float* gt      = (const float*)d_in[1];
  const float* im_info = (const float*)d_in[2];
  const float4* anchors = (const float4*)d_in[3];
  int N = in_sizes[3] / 4;             // 331776
  int G = in_sizes[1] / 5;             // 128
  if (G > GMAX) G = GMAX;
  float* out = (float*)d_out;

  // ws layout (~1.8 MB total)
  uint8_t* w = (uint8_t*)d_ws;
  uint32_t* scalars = (uint32_t*)w;                  //   128 B
  float*    gt_max  = (float*)(w + 512);             //   512 B
  uint32_t* hist    = (uint32_t*)(w + 1024);         //  32 KB (fg then bg)
  uint8_t* p = w + 1024 + 2 * NBINS * 4;
  int*   fcIdx = (int*)p;   p += CAND_CAP * 4;
  float* fcVal = (float*)p; p += CAND_CAP * 4;
  int*   bcIdx = (int*)p;   p += CAND_CAP * 4;
  float* bcVal = (float*)p; p += CAND_CAP * 4;
  int*    amax  = (int*)p;  p += (size_t)N * 4;
  int8_t* label = (int8_t*)p;

  // fg/bg lists staged in d_out's target region [N,5N) — rewritten by k_output last
  int*   fgIdx = (int*)(out + (size_t)N);
  float* fgVal = (float*)(out + 2 * (size_t)N);
  int*   bgIdx = (int*)(out + 3 * (size_t)N);
  float* bgVal = (float*)(out + 4 * (size_t)N);

  int nb = (N + 255) / 256;
  k_init<<<(2 * NBINS + 255) / 256, 256, 0, stream>>>(scalars, hist);
  k_gt_max<<<G, 256, 0, stream>>>(anchors, gt, im_info, N, gt_max);
  k_labels<<<nb, 256, 0, stream>>>(anchors, gt, im_info, N, G, gt_max, amax, label,
                                   scalars, hist, hist + NBINS, fgIdx, fgVal, bgIdx, bgVal);
  k_select<<<1, 64, 0, stream>>>(scalars, hist);
  k_cands<<<nb, 256, 0, stream>>>(scalars, label, fgIdx, fgVal, bgIdx, bgVal,
                                  fcIdx, fcVal, bcIdx, bcVal);
  k_rank<<<1, 256, 0, stream>>>(scalars, label, fcIdx, fcVal, bcIdx, bcVal);
  k_output<<<nb, 256, 0, stream>>>(anchors, gt, im_info, N, amax, label, scalars, out);
}

// Round 2
// 161.868 us; speedup vs baseline: 3.4480x; 3.4480x over previous
//
#include <hip/hip_runtime.h>
#include <stdint.h>

// AnchorTargetLayer for MI355X.
// N = 331776 anchors (192*192*9), G = 128 gt boxes.
// Outputs (flat in d_out, all float32):
//   [0,N)      labels (-1/0/1)
//   [N,5N)     bbox targets (4 per anchor)
//   [5N,9N)    inside weights
//   [9N,13N)   outside weights
#define TF_PARTITIONABLE 1

#define NBINS 4096
#define CAND_CAP 4096
#define GMAX 128
#define RPN_NEG 0.3f
#define RPN_POS 0.7f

struct U2 { uint32_t a, b; };

__host__ __device__ constexpr U2 tf2x32(uint32_t k0, uint32_t k1, uint32_t x0, uint32_t x1) {
  uint32_t ks2 = k0 ^ k1 ^ 0x1BD11BDAu;
  x0 += k0; x1 += k1;
#define TFR(r) { x0 += x1; x1 = (uint32_t)((x1 << (r)) | (x1 >> (32 - (r)))); x1 ^= x0; }
  TFR(13) TFR(15) TFR(26) TFR(6)
  x0 += k1; x1 += ks2 + 1u;
  TFR(17) TFR(29) TFR(16) TFR(24)
  x0 += ks2; x1 += k0 + 2u;
  TFR(13) TFR(15) TFR(26) TFR(6)
  x0 += k0; x1 += k1 + 3u;
  TFR(17) TFR(29) TFR(16) TFR(24)
  x0 += k1; x1 += ks2 + 4u;
  TFR(13) TFR(15) TFR(26) TFR(6)
  x0 += ks2; x1 += k0 + 5u;
#undef TFR
  return U2{x0, x1};
}

#if TF_PARTITIONABLE
constexpr U2 KEYF = tf2x32(0u, 42u, 0u, 0u);
constexpr U2 KEYB = tf2x32(0u, 42u, 0u, 1u);
#else
constexpr U2 C02 = tf2x32(0u, 42u, 0u, 2u);
constexpr U2 C13 = tf2x32(0u, 42u, 1u, 3u);
constexpr U2 KEYF = U2{C02.a, C13.a};
constexpr U2 KEYB = U2{C02.b, C13.b};
#endif

__device__ __forceinline__ float tf_uniform(uint32_t k0, uint32_t k1, uint32_t i, uint32_t N) {
#if TF_PARTITIONABLE
  U2 r = tf2x32(k0, k1, 0u, i);
  uint32_t bits = r.a ^ r.b;
#else
  uint32_t h = N >> 1;
  uint32_t bits;
  if (i < h) { U2 r = tf2x32(k0, k1, i, i + h); bits = r.a; }
  else       { U2 r = tf2x32(k0, k1, i - h, i); bits = r.b; }
#endif
  return __uint_as_float((bits >> 9) | 0x3f800000u) - 1.0f;
}

// order-preserving float<->uint map (works for negatives) for atomicMax
__device__ __forceinline__ uint32_t ordf(float f) {
  uint32_t u = __float_as_uint(f);
  return (u & 0x80000000u) ? ~u : (u | 0x80000000u);
}
__device__ __forceinline__ float unordf(uint32_t k) {
  uint32_t u = (k & 0x80000000u) ? (k & 0x7fffffffu) : ~k;
  return __uint_as_float(u);
}
#define ORD_NEG1 0x407FFFFFu  // ordf(-1.0f)

__global__ __launch_bounds__(256) void k_init(uint32_t* scalars, uint32_t* hist, uint32_t* gt_max_ord) {
  int i = blockIdx.x * 256 + threadIdx.x;
  if (i < 32) scalars[i] = 0u;
  if (i < GMAX) gt_max_ord[i] = ORD_NEG1;
  if (i < 2 * NBINS) hist[i] = 0u;
}

// anchor-parallel per-gt max: block stages 256 anchors in LDS, transposed loop,
// one global atomicMax per (gt, block).
__global__ __launch_bounds__(256) void k_gt_max(const float4* __restrict__ anchors,
                                                const float* __restrict__ gt,
                                                const float* __restrict__ im_info,
                                                int N, int G, uint32_t* __restrict__ gt_max_ord) {
#pragma clang fp contract(off)
  __shared__ float4 sA[256];
  __shared__ float sArea[256];   // anchor Pascal area; <0 => outside image
  __shared__ float sMax[256];
  int tid = threadIdx.x;
  int i = blockIdx.x * 256 + tid;
  float imH = im_info[0], imW = im_info[1];
  float4 a = make_float4(0.0f, 0.0f, -3.0f, -3.0f);
  if (i < N) a = anchors[i];
  bool inside = (a.x >= 0.0f && a.y >= 0.0f && a.z < imW && a.w < imH);
  float area = (a.z - a.x + 1.0f) * (a.w - a.y + 1.0f);
  sA[tid] = a;
  sArea[tid] = inside ? area : -1.0f;
  __syncthreads();

  int nparts = 256 / G;                  // >= 2 for G <= 128
  int g = tid % G, part = tid / G;
  float m = -1.0f;
  if (part < nparts) {
    float gx1 = gt[g * 5 + 0], gy1 = gt[g * 5 + 1], gx2 = gt[g * 5 + 2], gy2 = gt[g * 5 + 3];
    float ga = (gx2 - gx1 + 1.0f) * (gy2 - gy1 + 1.0f);
    int a0 = part * 256 / nparts, a1 = (part + 1) * 256 / nparts;
    for (int t = a0; t < a1; ++t) {
      float4 ab = sA[t];
      float aa = sArea[t];
      float iw = fmaxf(fminf(ab.z, gx2) - fmaxf(ab.x, gx1) + 1.0f, 0.0f);
      float ih = fmaxf(fminf(ab.w, gy2) - fmaxf(ab.y, gy1) + 1.0f, 0.0f);
      float inter = iw * ih;
      float v = inter / (aa + ga - inter);
      v = (aa >= 0.0f) ? v : -1.0f;      // outside rows contribute -1
      m = fmaxf(m, v);
    }
  }
  sMax[tid] = m;
  __syncthreads();
  if (tid < G) {
    for (int p = 1; p < nparts; ++p) m = fmaxf(m, sMax[tid + p * G]);
    atomicMax(&gt_max_ord[tid], ordf(m));
  }
}

// per-anchor: argmax, pre-subsample label; append fg/bg (idx,uniform) lists + histograms
__global__ __launch_bounds__(256) void k_labels(
    const float4* __restrict__ anchors, const float* __restrict__ gt,
    const float* __restrict__ im_info, int N, int G,
    const uint32_t* __restrict__ gt_max_ord, int* __restrict__ amax, int8_t* __restrict__ label,
    uint32_t* __restrict__ scalars, uint32_t* __restrict__ hist_f, uint32_t* __restrict__ hist_b,
    int* __restrict__ fgIdx, float* __restrict__ fgVal,
    int* __restrict__ bgIdx, float* __restrict__ bgVal) {
#pragma clang fp contract(off)
  __shared__ float4 sgt[GMAX];
  __shared__ float sga[GMAX];
  __shared__ float sgm[GMAX];
  __shared__ uint32_t lcnt[2], lbase[2];
  if (threadIdx.x < 2) lcnt[threadIdx.x] = 0u;
  for (int t = threadIdx.x; t < G; t += 256) {
    float gx1 = gt[t * 5 + 0], gy1 = gt[t * 5 + 1], gx2 = gt[t * 5 + 2], gy2 = gt[t * 5 + 3];
    sgt[t] = make_float4(gx1, gy1, gx2, gy2);
    sga[t] = (gx2 - gx1 + 1.0f) * (gy2 - gy1 + 1.0f);
    sgm[t] = unordf(gt_max_ord[t]);
  }
  __syncthreads();
  int i = blockIdx.x * 256 + threadIdx.x;
  int cls = -1;           // 0 = fg, 1 = bg
  float val = 0.0f;
  uint32_t my = 0u;
  if (i < N) {
    float4 a = anchors[i];
    float imH = im_info[0], imW = im_info[1];
    bool inside = (a.x >= 0.0f && a.y >= 0.0f && a.z < imW && a.w < imH);
    int lab = -1, am = 0;
    if (inside) {
      float aa = (a.z - a.x + 1.0f) * (a.w - a.y + 1.0f);
      float best = -1.0f;
      bool isbest = false;
      for (int g = 0; g < G; ++g) {
        float4 gb = sgt[g];
        float iw = fmaxf(fminf(a.z, gb.z) - fmaxf(a.x, gb.x) + 1.0f, 0.0f);
        float ih = fmaxf(fminf(a.w, gb.w) - fmaxf(a.y, gb.y) + 1.0f, 0.0f);
        float inter = iw * ih;
        float v = inter / (aa + sga[g] - inter);
        if (v > best) { best = v; am = g; }     // first-max == jnp.argmax
        if (v == sgm[g]) isbest = true;          // tie set vs per-gt max
      }
      if (best < RPN_NEG) lab = 0;
      if (isbest) lab = -lab;                    // -(-1)=1, -(0)=0 (quirk kept)
      if (best >= RPN_POS) lab = 1;
    }
    amax[i] = am;
    label[i] = (int8_t)lab;
    if (lab == 1) {
      cls = 0; val = tf_uniform(KEYF.a, KEYF.b, (uint32_t)i, (uint32_t)N);
      my = atomicAdd(&lcnt[0], 1u);
      int b = (int)(val * (float)NBINS); if (b > NBINS - 1) b = NBINS - 1;
      atomicAdd(&hist_f[b], 1u);
    } else if (lab == 0) {
      cls = 1; val = tf_uniform(KEYB.a, KEYB.b, (uint32_t)i, (uint32_t)N);
      my = atomicAdd(&lcnt[1], 1u);
      int b = (int)(val * (float)NBINS); if (b > NBINS - 1) b = NBINS - 1;
      atomicAdd(&hist_b[b], 1u);
    }
  }
  __syncthreads();
  if (threadIdx.x == 0) {
    lbase[0] = lcnt[0] ? atomicAdd(&scalars[0], lcnt[0]) : 0u;
    lbase[1] = lcnt[1] ? atomicAdd(&scalars[1], lcnt[1]) : 0u;
  }
  __syncthreads();
  if (cls == 0) { uint32_t p = lbase[0] + my; fgIdx[p] = i; fgVal[p] = val; }
  else if (cls == 1) { uint32_t p = lbase[1] + my; bgIdx[p] = i; bgVal[p] = val; }
}

// find cutoff buckets: smallest T with cum(0..T) >= k; base = cum(0..T-1)
__global__ void k_select(uint32_t* scalars, const uint32_t* __restrict__ hist) {
  if (threadIdx.x != 0 || blockIdx.x != 0) return;
  uint32_t F = scalars[0], B = scalars[1];
  uint32_t k_f = F > 128u ? 128u : F;
  uint32_t k_b = 256u - k_f;
  uint32_t T_f = NBINS, base_f = 0u;
  if (F > k_f) {
    uint32_t cum = 0u;
    for (int b = 0; b < NBINS; ++b) {
      uint32_t c = hist[b];
      if (cum + c >= k_f) { T_f = (uint32_t)b; base_f = cum; break; }
      cum += c;
    }
  }
  uint32_t T_b = NBINS, base_b = 0u;
  if (B > k_b) {
    uint32_t cum = 0u;
    for (int b = 0; b < NBINS; ++b) {
      uint32_t c = hist[NBINS + b];
      if (cum + c >= k_b) { T_b = (uint32_t)b; base_b = cum; break; }
      cum += c;
    }
  }
  uint32_t kept = k_f + (B < k_b ? B : k_b);
  scalars[4] = T_f; scalars[5] = base_f;
  scalars[6] = T_b; scalars[7] = base_b;
  scalars[8] = k_b; scalars[9] = k_f;
  ((float*)scalars)[12] = kept ? (1.0f / (float)kept) : 0.0f;  // 1/num_ex
}

// drop entries past cutoff bucket; collect cutoff-bucket candidates
__global__ __launch_bounds__(256) void k_cands(uint32_t* scalars, int8_t* __restrict__ label,
    const int* __restrict__ fgIdx, const float* __restrict__ fgVal,
    const int* __restrict__ bgIdx, const float* __restrict__ bgVal,
    int* __restrict__ fcIdx, float* __restrict__ fcVal,
    int* __restrict__ bcIdx, float* __restrict__ bcVal) {
  uint32_t j = blockIdx.x * 256 + threadIdx.x;
  uint32_t F = scalars[0], B = scalars[1];
  uint32_t T_f = scalars[4], T_b = scalars[6];
  if (j < F) {
    float v = fgVal[j];
    uint32_t b = (uint32_t)(v * (float)NBINS); if (b > NBINS - 1) b = NBINS - 1;
    if (b > T_f) label[fgIdx[j]] = -1;
    else if (b == T_f) {
      uint32_t p = atomicAdd(&scalars[2], 1u);
      if (p < CAND_CAP) { fcIdx[p] = fgIdx[j]; fcVal[p] = v; }
    }
  }
  if (j < B) {
    float v = bgVal[j];
    uint32_t b = (uint32_t)(v * (float)NBINS); if (b > NBINS - 1) b = NBINS - 1;
    if (b > T_b) label[bgIdx[j]] = -1;
    else if (b == T_b) {
      uint32_t p = atomicAdd(&scalars[3], 1u);
      if (p < CAND_CAP) { bcIdx[p] = bgIdx[j]; bcVal[p] = v; }
    }
  }
}

// exact stable rank (value, then index — matches stable argsort) within cutoff bucket
__global__ __launch_bounds__(256) void k_rank(const uint32_t* __restrict__ scalars,
    int8_t* __restrict__ label,
    const int* __restrict__ fcIdx, const float* __restrict__ fcVal,
    const int* __restrict__ bcIdx, const float* __restrict__ bcVal) {
  uint32_t nf = scalars[2]; if (nf > CAND_CAP) nf = CAND_CAP;
  uint32_t nb = scalars[3]; if (nb > CAND_CAP) nb = CAND_CAP;
  uint32_t base_f = scalars[5], base_b = scalars[7];
  uint32_t k_f = scalars[9], k_b = scalars[8];
  for (uint32_t c = threadIdx.x; c < nf; c += 256) {
    float v = fcVal[c]; int idx = fcIdx[c];
    uint32_t r = base_f;
    for (uint32_t c2 = 0; c2 < nf; ++c2) {
      float v2 = fcVal[c2]; int i2 = fcIdx[c2];
      if (v2 < v || (v2 == v && i2 < idx)) r++;
    }
    if (r >= k_f) label[idx] = -1;
  }
  for (uint32_t c = threadIdx.x; c < nb; c += 256) {
    float v = bcVal[c]; int idx = bcIdx[c];
    uint32_t r = base_b;
    for (uint32_t c2 = 0; c2 < nb; ++c2) {
      float v2 = bcVal[c2]; int i2 = bcIdx[c2];
      if (v2 < v || (v2 == v && i2 < idx)) r++;
    }
    if (r >= k_b) label[idx] = -1;
  }
}

__global__ __launch_bounds__(256) void k_output(const float4* __restrict__ anchors,
    const float* __restrict__ gt, const float* __restrict__ im_info, int N,
    const int* __restrict__ amax, const int8_t* __restrict__ label,
    const uint32_t* __restrict__ scalars, float* __restrict__ out) {
#pragma clang fp contract(off)
  int i = blockIdx.x * 256 + threadIdx.x;
  if (i >= N) return;
  float4 a = anchors[i];
  float imH = im_info[0], imW = im_info[1];
  bool inside = (a.x >= 0.0f && a.y >= 0.0f && a.z < imW && a.w < imH);
  int lab = label[i];
  out[i] = (float)lab;
  float4 t = make_float4(0.0f, 0.0f, 0.0f, 0.0f);
  if (inside) {
    int g = amax[i];
    float gx1 = gt[g * 5 + 0], gy1 = gt[g * 5 + 1], gx2 = gt[g * 5 + 2], gy2 = gt[g * 5 + 3];
    float ew = a.z - a.x + 1.0f, eh = a.w - a.y + 1.0f;
    float ecx = a.x + 0.5f * ew, ecy = a.y + 0.5f * eh;
    float gw = gx2 - gx1 + 1.0f, gh = gy2 - gy1 + 1.0f;
    float gcx = gx1 + 0.5f * gw, gcy = gy1 + 0.5f * gh;
    t.x = (gcx - ecx) / ew;
    t.y = (gcy - ecy) / eh;
    t.z = logf(gw / ew);
    t.w = logf(gh / eh);
  }
  ((float4*)(out + (size_t)N))[i] = t;
  float iw = (lab == 1) ? 1.0f : 0.0f;
  ((float4*)(out + 5 * (size_t)N))[i] = make_float4(iw, iw, iw, iw);
  float inv = ((const float*)scalars)[12];
  float ow = (lab == 0 || lab == 1) ? inv : 0.0f;
  ((float4*)(out + 9 * (size_t)N))[i] = make_float4(ow, ow, ow, ow);
}

extern "C" void kernel_launch(void* const* d_in, const int* in_sizes, int n_in,
                              void* d_out, int out_size, void* d_ws, size_t ws_size,
                              hipStream_t stream) {
  const float* gt      = (const float*)d_in[1];
  const float* im_info = (const float*)d_in[2];
  const float4* anchors = (const float4*)d_in[3];
  int N = in_sizes[3] / 4;             // 331776
  int G = in_sizes[1] / 5;             // 128
  if (G > GMAX) G = GMAX;
  float* out = (float*)d_out;

  // ws layout (~1.8 MB total)
  uint8_t* w = (uint8_t*)d_ws;
  uint32_t* scalars = (uint32_t*)w;                  //   128 B
  uint32_t* gt_max_ord = (uint32_t*)(w + 512);       //   512 B
  uint32_t* hist    = (uint32_t*)(w + 1024);         //  32 KB (fg then bg)
  uint8_t* p = w + 1024 + 2 * NBINS * 4;
  int*   fcIdx = (int*)p;   p += CAND_CAP * 4;
  float* fcVal = (float*)p; p += CAND_CAP * 4;
  int*   bcIdx = (int*)p;   p += CAND_CAP * 4;
  float* bcVal = (float*)p; p += CAND_CAP * 4;
  int*    amax  = (int*)p;  p += (size_t)N * 4;
  int8_t* label = (int8_t*)p;

  // fg/bg lists staged in d_out's target region [N,5N) — rewritten by k_output last
  int*   fgIdx = (int*)(out + (size_t)N);
  float* fgVal = (float*)(out + 2 * (size_t)N);
  int*   bgIdx = (int*)(out + 3 * (size_t)N);
  float* bgVal = (float*)(out + 4 * (size_t)N);

  int nb = (N + 255) / 256;
  k_init<<<(2 * NBINS + 255) / 256, 256, 0, stream>>>(scalars, hist, gt_max_ord);
  k_gt_max<<<nb, 256, 0, stream>>>(anchors, gt, im_info, N, G, gt_max_ord);
  k_labels<<<nb, 256, 0, stream>>>(anchors, gt, im_info, N, G, gt_max_ord, amax, label,
                                   scalars, hist, hist + NBINS, fgIdx, fgVal, bgIdx, bgVal);
  k_select<<<1, 64, 0, stream>>>(scalars, hist);
  k_cands<<<nb, 256, 0, stream>>>(scalars, label, fgIdx, fgVal, bgIdx, bgVal,
                                  fcIdx, fcVal, bcIdx, bcVal);
  k_rank<<<1, 256, 0, stream>>>(scalars, label, fcIdx, fcVal, bcIdx, bcVal);
  k_output<<<nb, 256, 0, stream>>>(anchors, gt, im_info, N, amax, label, scalars, out);
}